// Round 5
// baseline (124.541 us; speedup 1.0000x reference)
//
#include <hip/hip_runtime.h>
#include <hip/hip_bf16.h>

// DCNv2: B=4, C=64, H=W=128, O=64, KS=3, N=9, PAD=1. I/O float32.
#define BB 4
#define CC 64
#define HH 128
#define WW 128
#define OO 64
#define NN 9
#define HW 16384
#define HP 130
#define WP 130

// ---- ws layout (float-slot offsets) ----
// 0        wpmb bf16 [32][576]   (rows 0..17 w_p, 18..26 w_m, 27..31 zero) = 9216 f
// 9216     bias fp32 (18 b_p then 9 b_m) = 27 f
// 9248     wcb  bf16 [o(64)][K(576)], K = kt*64+c = 18432 f
// 27680    xt   bf16 [b][hw][c] = 2097152 f
#define WPMB_F  0
#define BPM_OFF 9216
#define WCB_F   9248
#define XT_F    27680

typedef __attribute__((ext_vector_type(8))) short s8v;
typedef __attribute__((ext_vector_type(8))) unsigned short u8v;
typedef __attribute__((ext_vector_type(4))) float f4v;

__device__ __forceinline__ unsigned short f2bu(float f) {   // fp32 -> bf16 bits (RNE)
    unsigned int b = __float_as_uint(f);
    return (unsigned short)((b + 0x7FFFu + ((b >> 16) & 1u)) >> 16);
}
__device__ __forceinline__ float bu2f(unsigned short u) {
    return __uint_as_float(((unsigned int)u) << 16);
}

__global__ void k_prep(const float* __restrict__ wp,
                       const float* __restrict__ bp,
                       const float* __restrict__ wm,
                       const float* __restrict__ bm,
                       const float* __restrict__ wcv,
                       float* __restrict__ ws) {
    int tid = blockIdx.x * blockDim.x + threadIdx.x;
    if (tid < 18432) {                       // wpmb [32][576]
        int r = tid / 576;
        int kk = tid % 576;                  // kk = kt*64 + c
        int kt = kk >> 6;
        int c = kk & 63;
        int dy = kt / 3, dx = kt % 3;
        float v = 0.f;
        if (r < 18)       v = wp[((r * 64 + c) * 3 + dy) * 3 + dx];
        else if (r < 27)  v = wm[(((r - 18) * 64 + c) * 3 + dy) * 3 + dx];
        ((unsigned short*)(ws + WPMB_F))[tid] = f2bu(v);
    } else if (tid < 18459) {
        int i = tid - 18432;
        ws[BPM_OFF + i] = (i < 18) ? bp[i] : bm[i - 18];
    } else if (tid >= 20480 && tid < 20480 + 36864) {   // wcb [64][576]
        int d = tid - 20480;
        int o = d / 576;
        int kk = d % 576;
        int kt = kk >> 6;
        int c = kk & 63;
        ((unsigned short*)(ws + WCB_F))[o * 576 + kk] = f2bu(wcv[(o * 64 + c) * 9 + kt]);
    }
}

// NCHW fp32 -> NHWC bf16 transpose, 64x64 LDS tiles.
__global__ void __launch_bounds__(256) k_xt(const float* __restrict__ x,
                                            float* __restrict__ ws) {
    __shared__ unsigned short tile[64][66];
    int blk = blockIdx.x;          // 4 b * 256 hw-tiles
    int b = blk >> 8;
    int hw0 = (blk & 255) * 64;
    int t = threadIdx.x;
    unsigned short* xt = (unsigned short*)(ws + XT_F);

#pragma unroll
    for (int p = 0; p < 16; p++) {
        int c = p * 4 + (t >> 6);
        int i = t & 63;
        tile[c][i] = f2bu(x[((size_t)(b * 64 + c)) * HW + hw0 + i]);
    }
    __syncthreads();
#pragma unroll
    for (int p = 0; p < 16; p++) {
        int i = p * 4 + (t >> 6);
        int c = t & 63;
        xt[((size_t)(b * HW + hw0 + i)) * 64 + c] = tile[c][i];
    }
}

// Fused: offset/mod conv (MFMA, halo B-tile) -> p/m in LDS -> sampler + MFMA einsum.
// One block per 64-pixel row tile. LDS: halo 28512 B (phase 1), aliased by
// S [0,9216) + A2 [9216,18432) in phase 2; pm at 28512..35424.
__global__ void __launch_bounds__(256) k_fused(const float* __restrict__ ws,
                                               float* __restrict__ out) {
    __shared__ char ldsbuf[35424];
    unsigned short* halo = (unsigned short*)ldsbuf;          // [3][66][72]
    unsigned short* Sld  = (unsigned short*)ldsbuf;          // [64][72] (phase 2)
    unsigned short* A2ld = (unsigned short*)(ldsbuf + 9216); // [64][72] (phase 2)
    float* pm = (float*)(ldsbuf + 28512);                    // [27][64]

    int t = threadIdx.x;
    int lane = t & 63;
    int wid = t >> 6;
    int ln15 = lane & 15;
    int quad = lane >> 4;

    int blk = blockIdx.x;            // 1024: 4 b * 256 tiles
    int b = blk >> 8;
    int hw0 = (blk & 255) * 64;
    int h = hw0 >> 7;
    int w0 = hw0 & 127;

    const unsigned short* wpmb = (const unsigned short*)(ws + WPMB_F);
    const unsigned short* wcb  = (const unsigned short*)(ws + WCB_F);
    const unsigned short* xtb  = (const unsigned short*)(ws + XT_F) + (size_t)b * HW * 64;
    const float* bpm = ws + BPM_OFF;

    // ---- stage halo: rows h-1..h+1, cols w0-1..w0+64, 64ch each ----
    {
        u8v z = (u8v){0, 0, 0, 0, 0, 0, 0, 0};
#pragma unroll
        for (int i = 0; i < 4; i++) {
            int s = t + i * 256;
            if (s < 792) {                 // 3*66 rows x 4 ch-groups
                int cg = s & 3;
                int rc = s >> 2;           // 0..197
                int col = rc % 66;
                int r = rc / 66;
                int h2 = h + r - 1;
                int w2 = w0 + col - 1;
                bool val = ((unsigned)h2 < 128u) && ((unsigned)w2 < 128u);
                u8v e0 = z, e1 = z;
                if (val) {
                    const unsigned short* src = xtb + ((size_t)(h2 * 128 + w2)) * 64 + cg * 16;
                    e0 = *(const u8v*)(src);
                    e1 = *(const u8v*)(src + 8);
                }
                unsigned short* dst = halo + (r * 66 + col) * 72 + cg * 16;
                *(u8v*)(dst) = e0;
                *(u8v*)(dst + 8) = e1;
            }
        }
    }
    __syncthreads();

    // ---- phase 1: offset conv GEMM, M=32(27 used), N=64 pixels, K=576 ----
    f4v acc1[2];
    acc1[0] = (f4v){0.f, 0.f, 0.f, 0.f};
    acc1[1] = (f4v){0.f, 0.f, 0.f, 0.f};

#pragma unroll 1
    for (int kt = 0; kt < 9; kt++) {
        int dy = kt / 3, dx = kt % 3;
#pragma unroll
        for (int ks = 0; ks < 2; ks++) {
            int cs = ks * 32 + quad * 8;
            s8v bf = *(const s8v*)(&halo[(dy * 66 + wid * 16 + ln15 + dx) * 72 + cs]);
#pragma unroll
            for (int mt = 0; mt < 2; mt++) {
                s8v af = *(const s8v*)(wpmb + (mt * 16 + ln15) * 576 + kt * 64 + cs);
                acc1[mt] = __builtin_amdgcn_mfma_f32_16x16x32_bf16(af, bf, acc1[mt], 0, 0, 0);
            }
        }
    }

    // epilogue: D col=pixel(wid*16+ln15), row=oc(mt*16+quad*4+r) -> pm[oc][pix]
    {
        int n = wid * 16 + ln15;
        int pw = w0 + n;
#pragma unroll
        for (int mt = 0; mt < 2; mt++) {
#pragma unroll
            for (int r = 0; r < 4; r++) {
                int oc = mt * 16 + quad * 4 + r;
                if (oc < 27) {
                    float v = acc1[mt][r] + bpm[oc];
                    if (oc < 9) {
                        v += (float)(oc / 3 - 1) + (float)(h + 1);
                    } else if (oc < 18) {
                        int k = oc - 9;
                        v += (float)(k % 3 - 1) + (float)(pw + 1);
                    } else {
                        v = 1.f / (1.f + __expf(-v));
                    }
                    pm[oc * 64 + n] = v;
                }
            }
        }
    }
    __syncthreads();   // pm visible; all halo reads done (S/A2 may overwrite)

    // ---- phase 2: sampler + main GEMM, M=64 oc, N=64 pixels, K=576 ----
    int p_loc = t >> 2;              // pixel within tile (sampling role)
    int cq = t & 3;                  // 16-channel group

    f4v acc[4];
#pragma unroll
    for (int mt = 0; mt < 4; mt++) acc[mt] = (f4v){0.f, 0.f, 0.f, 0.f};

#pragma unroll 1
    for (int kt = 0; kt < 9; kt++) {
        float px = pm[kt * 64 + p_loc];
        float py = pm[(9 + kt) * 64 + p_loc];
        float mk = pm[(18 + kt) * 64 + p_loc];

        float fx = floorf(px), fy = floorf(py);
        float pxc = fminf(fmaxf(px, 0.f), (float)(HP - 1));
        float pyc = fminf(fmaxf(py, 0.f), (float)(WP - 1));
        int qltx = (int)fminf(fmaxf(fx, 0.f), (float)(HP - 1));
        int qlty = (int)fminf(fmaxf(fy, 0.f), (float)(WP - 1));
        int qrbx = (int)fminf(fmaxf(fx + 1.f, 0.f), (float)(HP - 1));
        int qrby = (int)fminf(fmaxf(fy + 1.f, 0.f), (float)(WP - 1));

        float gltx = 1.f + ((float)qltx - pxc);
        float glty = 1.f + ((float)qlty - pyc);
        float grbx = 1.f - ((float)qrbx - pxc);
        float grby = 1.f - ((float)qrby - pyc);

        bool vlx = (qltx >= 1) && (qltx <= HH);
        bool vly = (qlty >= 1) && (qlty <= WW);
        bool vrx = (qrbx >= 1) && (qrbx <= HH);
        bool vry = (qrby >= 1) && (qrby <= WW);
        float g0 = (vlx && vly) ? gltx * glty * mk : 0.f;
        float g1 = (vrx && vry) ? grbx * grby * mk : 0.f;
        float g2 = (vlx && vry) ? gltx * grby * mk : 0.f;
        float g3 = (vrx && vly) ? grbx * glty * mk : 0.f;

        int xlt = min(max(qltx - 1, 0), HH - 1);
        int ylt = min(max(qlty - 1, 0), WW - 1);
        int xrb = min(max(qrbx - 1, 0), HH - 1);
        int yrb = min(max(qrby - 1, 0), WW - 1);
        size_t i0 = (size_t)(xlt * WW + ylt) * 64;
        size_t i1 = (size_t)(xrb * WW + yrb) * 64;
        size_t i2 = (size_t)(xlt * WW + yrb) * 64;
        size_t i3 = (size_t)(xrb * WW + ylt) * 64;

        __syncthreads();    // previous tap's MFMA reads done
        // stage A2: Wc[row][kt*64 .. +64), 16 ch per thread
        {
            int row = t >> 2, g = t & 3;
            const unsigned short* src = wcb + row * 576 + kt * 64 + g * 16;
            *(u8v*)(&A2ld[row * 72 + g * 16]) = *(const u8v*)(src);
            *(u8v*)(&A2ld[row * 72 + g * 16 + 8]) = *(const u8v*)(src + 8);
        }
        // sample S: 16 channels (cq*16..) for pixel p_loc
        {
            int cbase = cq * 16;
            const unsigned short* s0 = xtb + i0 + cbase;
            const unsigned short* s1 = xtb + i1 + cbase;
            const unsigned short* s2 = xtb + i2 + cbase;
            const unsigned short* s3 = xtb + i3 + cbase;
            u8v e0a = *(const u8v*)(s0), e0b = *(const u8v*)(s0 + 8);
            u8v e1a = *(const u8v*)(s1), e1b = *(const u8v*)(s1 + 8);
            u8v e2a = *(const u8v*)(s2), e2b = *(const u8v*)(s2 + 8);
            u8v e3a = *(const u8v*)(s3), e3b = *(const u8v*)(s3 + 8);
            u8v sva, svb;
#pragma unroll
            for (int j = 0; j < 8; j++) {
                float va = g0 * bu2f(e0a[j]) + g1 * bu2f(e1a[j])
                         + g2 * bu2f(e2a[j]) + g3 * bu2f(e3a[j]);
                float vb = g0 * bu2f(e0b[j]) + g1 * bu2f(e1b[j])
                         + g2 * bu2f(e2b[j]) + g3 * bu2f(e3b[j]);
                sva[j] = f2bu(va);
                svb[j] = f2bu(vb);
            }
            *(u8v*)(&Sld[p_loc * 72 + cbase]) = sva;
            *(u8v*)(&Sld[p_loc * 72 + cbase + 8]) = svb;
        }
        __syncthreads();

#pragma unroll
        for (int ks = 0; ks < 2; ks++) {
            s8v bf = *(const s8v*)(&Sld[(wid * 16 + ln15) * 72 + ks * 32 + quad * 8]);
#pragma unroll
            for (int mt = 0; mt < 4; mt++) {
                s8v af = *(const s8v*)(&A2ld[(mt * 16 + ln15) * 72 + ks * 32 + quad * 8]);
                acc[mt] = __builtin_amdgcn_mfma_f32_16x16x32_bf16(af, bf, acc[mt], 0, 0, 0);
            }
        }
    }

    // epilogue: D col = pixel, row = oc
    int pix = hw0 + wid * 16 + ln15;
    float* ob = out + (size_t)b * (OO * HW) + pix;
#pragma unroll
    for (int mt = 0; mt < 4; mt++) {
#pragma unroll
        for (int r = 0; r < 4; r++) {
            ob[(size_t)(mt * 16 + quad * 4 + r) * HW] = acc[mt][r];
        }
    }
}

extern "C" void kernel_launch(void* const* d_in, const int* in_sizes, int n_in,
                              void* d_out, int out_size, void* d_ws, size_t ws_size,
                              hipStream_t stream) {
    const float* x   = (const float*)d_in[0];
    const float* wp  = (const float*)d_in[1];
    const float* bp  = (const float*)d_in[2];
    const float* wm  = (const float*)d_in[3];
    const float* bm  = (const float*)d_in[4];
    const float* wcv = (const float*)d_in[5];
    float* ws = (float*)d_ws;
    float* out = (float*)d_out;

    hipLaunchKernelGGL(k_prep, dim3(224), dim3(256), 0, stream, wp, bp, wm, bm, wcv, ws);
    hipLaunchKernelGGL(k_xt, dim3(1024), dim3(256), 0, stream, x, ws);
    hipLaunchKernelGGL(k_fused, dim3(1024), dim3(256), 0, stream, ws, out);
}